// Round 1
// baseline (978.683 us; speedup 1.0000x reference)
//
#include <hip/hip_runtime.h>
#include <math.h>

// Problem constants: B=2, S=2048, E=1024, H=16, HD=64
// ws layout (floats):
//   tab : [2048][32] float2 (cos,sin)     -> 131072 floats
//   q   : [B][H][S][HD]                   -> 4194304 floats
//   k   : same
//   v   : same
//   o   : [B][S][E]                       -> 4194304 floats
static const size_t TAB_OFF = 0;
static const size_t Q_OFF = 131072;
static const size_t K_OFF = Q_OFF + 4194304;
static const size_t V_OFF = K_OFF + 4194304;
static const size_t O_OFF = V_OFF + 4194304;

__global__ __launch_bounds__(256) void rope_table_kernel(float2* __restrict__ tab) {
  int idx = blockIdx.x * 256 + threadIdx.x;
  if (idx >= 2048 * 32) return;
  int s = idx >> 5;
  int i = idx & 31;
  double theta = pow(10000.0, -((double)(2 * i)) / 64.0);
  float ang = (float)s * (float)theta;
  tab[idx] = make_float2(cosf(ang), sinf(ang));
}

// qkv[m][n] = sum_e x[m][e] * w1[n][e];  M=4096, N=3072, K=1024
// epilogue: interleaved RoPE on q/k, scatter to [B][H][S][HD] fp32 in ws.
__global__ __launch_bounds__(256) void gemm_qkv_rope(
    const float* __restrict__ x, const float* __restrict__ w1,
    const float2* __restrict__ tab, float* __restrict__ qws,
    float* __restrict__ kws, float* __restrict__ vws) {
  __shared__ float As[16][68];
  __shared__ float Bs[16][68];
  const int bm = blockIdx.x / 48;
  const int bn = blockIdx.x % 48;
  const int m0 = bm << 6;
  const int n0 = bn << 6;
  const int t = threadIdx.x;
  const int lrow = t >> 2;
  const int lk = (t & 3) << 2;
  const int tx = t & 15;
  const int ty = t >> 4;
  const float* ap = x + (m0 + lrow) * 1024 + lk;
  const float* bp = w1 + (n0 + lrow) * 1024 + lk;
  float acc[4][4] = {};
  for (int k0 = 0; k0 < 1024; k0 += 16) {
    float4 av = *(const float4*)(ap + k0);
    float4 bv = *(const float4*)(bp + k0);
    As[lk + 0][lrow] = av.x;
    As[lk + 1][lrow] = av.y;
    As[lk + 2][lrow] = av.z;
    As[lk + 3][lrow] = av.w;
    Bs[lk + 0][lrow] = bv.x;
    Bs[lk + 1][lrow] = bv.y;
    Bs[lk + 2][lrow] = bv.z;
    Bs[lk + 3][lrow] = bv.w;
    __syncthreads();
#pragma unroll
    for (int kk = 0; kk < 16; ++kk) {
      float4 a4 = *(const float4*)&As[kk][ty << 2];
      float4 b4 = *(const float4*)&Bs[kk][tx << 2];
      float aa[4] = {a4.x, a4.y, a4.z, a4.w};
      float bb[4] = {b4.x, b4.y, b4.z, b4.w};
#pragma unroll
      for (int i = 0; i < 4; ++i)
#pragma unroll
        for (int j = 0; j < 4; ++j) acc[i][j] += aa[i] * bb[j];
    }
    __syncthreads();
  }
  // Column block (64 cols) lies entirely inside one (which, head) since
  // n0 is a multiple of 64: which = q/k/v selector, h = head.
  const int which = n0 >> 10;
  const int h = (n0 & 1023) >> 6;
  const int d0 = tx << 2;
  float* dstbase = (which == 0) ? qws : ((which == 1) ? kws : vws);
#pragma unroll
  for (int i = 0; i < 4; ++i) {
    const int mrow = m0 + (ty << 2) + i;
    const int b = mrow >> 11;  // S = 2048
    const int s = mrow & 2047;
    float4 r;
    if (which == 2) {
      r.x = acc[i][0];
      r.y = acc[i][1];
      r.z = acc[i][2];
      r.w = acc[i][3];
    } else {
      // interleaved RoPE: pairs (d0,d0+1) and (d0+2,d0+3)
      float2 cs0 = tab[(s << 5) + (tx << 1)];
      float2 cs1 = tab[(s << 5) + (tx << 1) + 1];
      r.x = acc[i][0] * cs0.x - acc[i][1] * cs0.y;
      r.y = acc[i][1] * cs0.x + acc[i][0] * cs0.y;
      r.z = acc[i][2] * cs1.x - acc[i][3] * cs1.y;
      r.w = acc[i][3] * cs1.x + acc[i][2] * cs1.y;
    }
    *(float4*)&dstbase[(((size_t)(b * 16 + h) << 11) + s) * 64 + d0] = r;
  }
}

// Flash attention, fp32. One block = one (b, h, 64-row q tile). 256 threads.
// Thread (ty,tx) owns S[4 rows r0..r0+3][4 cols c0..c0+3]; row stats reduced
// over the 16 tx lanes (same wave). PV done as a second LDS GEMM via Pst.
__global__ __launch_bounds__(256) void attn_kernel(
    const float* __restrict__ qws, const float* __restrict__ kws,
    const float* __restrict__ vws, float* __restrict__ ows) {
  __shared__ float Qst[64][68];  // transposed: Qst[d][r], pre-scaled by 1/8
  __shared__ float Kst[64][68];  // transposed: Kst[d][j]
  __shared__ float Vsm[64][68];  // natural:   Vsm[j][d]
  __shared__ float Pst[64][68];  // transposed: Pst[j][r]
  const int blk = blockIdx.x;
  const int qt = blk & 31;
  const int h = (blk >> 5) & 15;
  const int b = blk >> 9;
  const int t = threadIdx.x;
  const int lr = t >> 2;
  const int ld = (t & 3) << 4;
  const int tx = t & 15;
  const int ty = t >> 4;
  const int r0 = ty << 2;
  const int c0 = tx << 2;
  const size_t hb = ((size_t)(b * 16 + h)) << 11;  // (b*H+h)*S
  const float* qb = qws + (hb + (size_t)qt * 64) * 64;
  const float* kb = kws + hb * 64;
  const float* vb = vws + hb * 64;
  // stage Q transposed + scaled
#pragma unroll
  for (int i = 0; i < 4; ++i) {
    float4 v = *(const float4*)&qb[lr * 64 + ld + (i << 2)];
    Qst[ld + (i << 2) + 0][lr] = v.x * 0.125f;
    Qst[ld + (i << 2) + 1][lr] = v.y * 0.125f;
    Qst[ld + (i << 2) + 2][lr] = v.z * 0.125f;
    Qst[ld + (i << 2) + 3][lr] = v.w * 0.125f;
  }
  float m[4], l[4], o[4][4];
#pragma unroll
  for (int i = 0; i < 4; ++i) {
    m[i] = -3.0e38f;
    l[i] = 0.0f;
#pragma unroll
    for (int j = 0; j < 4; ++j) o[i][j] = 0.0f;
  }
  for (int kt = 0; kt < 32; ++kt) {
    __syncthreads();  // prior tile's PV reads done before restaging
    const float* kbt = kb + kt * 64 * 64;
    const float* vbt = vb + kt * 64 * 64;
#pragma unroll
    for (int i = 0; i < 4; ++i) {
      float4 kv = *(const float4*)&kbt[lr * 64 + ld + (i << 2)];
      Kst[ld + (i << 2) + 0][lr] = kv.x;
      Kst[ld + (i << 2) + 1][lr] = kv.y;
      Kst[ld + (i << 2) + 2][lr] = kv.z;
      Kst[ld + (i << 2) + 3][lr] = kv.w;
      float4 vv = *(const float4*)&vbt[lr * 64 + ld + (i << 2)];
      *(float4*)&Vsm[lr][ld + (i << 2)] = vv;
    }
    __syncthreads();
    // S = Q K^T (pre-scaled)
    float sacc[4][4] = {};
#pragma unroll 4
    for (int d = 0; d < 64; ++d) {
      float4 q4 = *(const float4*)&Qst[d][r0];
      float4 k4 = *(const float4*)&Kst[d][c0];
      float qa[4] = {q4.x, q4.y, q4.z, q4.w};
      float ka[4] = {k4.x, k4.y, k4.z, k4.w};
#pragma unroll
      for (int i = 0; i < 4; ++i)
#pragma unroll
        for (int j = 0; j < 4; ++j) sacc[i][j] += qa[i] * ka[j];
    }
    // online softmax
    float mt[4], fac[4], ls[4];
#pragma unroll
    for (int i = 0; i < 4; ++i)
      mt[i] =
          fmaxf(fmaxf(sacc[i][0], sacc[i][1]), fmaxf(sacc[i][2], sacc[i][3]));
#pragma unroll
    for (int off = 1; off < 16; off <<= 1)
#pragma unroll
      for (int i = 0; i < 4; ++i) mt[i] = fmaxf(mt[i], __shfl_xor(mt[i], off));
#pragma unroll
    for (int i = 0; i < 4; ++i) {
      const float mn = fmaxf(m[i], mt[i]);
      fac[i] = __expf(m[i] - mn);
      m[i] = mn;
      float p0 = __expf(sacc[i][0] - mn);
      float p1 = __expf(sacc[i][1] - mn);
      float p2 = __expf(sacc[i][2] - mn);
      float p3 = __expf(sacc[i][3] - mn);
      sacc[i][0] = p0;
      sacc[i][1] = p1;
      sacc[i][2] = p2;
      sacc[i][3] = p3;
      ls[i] = (p0 + p1) + (p2 + p3);
    }
#pragma unroll
    for (int off = 1; off < 16; off <<= 1)
#pragma unroll
      for (int i = 0; i < 4; ++i) ls[i] += __shfl_xor(ls[i], off);
#pragma unroll
    for (int i = 0; i < 4; ++i) {
      l[i] = l[i] * fac[i] + ls[i];
#pragma unroll
      for (int j = 0; j < 4; ++j) o[i][j] *= fac[i];
    }
#pragma unroll
    for (int i = 0; i < 4; ++i)
#pragma unroll
      for (int j = 0; j < 4; ++j) Pst[c0 + j][r0 + i] = sacc[i][j];
    __syncthreads();
    // O += P V
#pragma unroll 4
    for (int j = 0; j < 64; ++j) {
      float4 p4 = *(const float4*)&Pst[j][r0];
      float4 v4 = *(const float4*)&Vsm[j][c0];
      float pa[4] = {p4.x, p4.y, p4.z, p4.w};
      float va[4] = {v4.x, v4.y, v4.z, v4.w};
#pragma unroll
      for (int i = 0; i < 4; ++i)
#pragma unroll
        for (int dd = 0; dd < 4; ++dd) o[i][dd] += pa[i] * va[dd];
    }
  }
  // epilogue: normalize, write o[b][s][h*64+d]
#pragma unroll
  for (int i = 0; i < 4; ++i) {
    const float inv = 1.0f / l[i];
    float4 r;
    r.x = o[i][0] * inv;
    r.y = o[i][1] * inv;
    r.z = o[i][2] * inv;
    r.w = o[i][3] * inv;
    const int srow = (qt << 6) + r0 + i;
    *(float4*)&ows[((size_t)(b * 2048 + srow) << 10) + (h << 6) + c0] = r;
  }
}

// out[m][n] = sum_e o[m][e] * w2[n][e];  M=4096, N=1024, K=1024
__global__ __launch_bounds__(256) void gemm_out(const float* __restrict__ o,
                                                const float* __restrict__ w2,
                                                float* __restrict__ out) {
  __shared__ float As[16][68];
  __shared__ float Bs[16][68];
  const int bm = blockIdx.x >> 4;
  const int bn = blockIdx.x & 15;
  const int m0 = bm << 6;
  const int n0 = bn << 6;
  const int t = threadIdx.x;
  const int lrow = t >> 2;
  const int lk = (t & 3) << 2;
  const int tx = t & 15;
  const int ty = t >> 4;
  const float* ap = o + (m0 + lrow) * 1024 + lk;
  const float* bp = w2 + (n0 + lrow) * 1024 + lk;
  float acc[4][4] = {};
  for (int k0 = 0; k0 < 1024; k0 += 16) {
    float4 av = *(const float4*)(ap + k0);
    float4 bv = *(const float4*)(bp + k0);
    As[lk + 0][lrow] = av.x;
    As[lk + 1][lrow] = av.y;
    As[lk + 2][lrow] = av.z;
    As[lk + 3][lrow] = av.w;
    Bs[lk + 0][lrow] = bv.x;
    Bs[lk + 1][lrow] = bv.y;
    Bs[lk + 2][lrow] = bv.z;
    Bs[lk + 3][lrow] = bv.w;
    __syncthreads();
#pragma unroll
    for (int kk = 0; kk < 16; ++kk) {
      float4 a4 = *(const float4*)&As[kk][ty << 2];
      float4 b4 = *(const float4*)&Bs[kk][tx << 2];
      float aa[4] = {a4.x, a4.y, a4.z, a4.w};
      float bb[4] = {b4.x, b4.y, b4.z, b4.w};
#pragma unroll
      for (int i = 0; i < 4; ++i)
#pragma unroll
        for (int j = 0; j < 4; ++j) acc[i][j] += aa[i] * bb[j];
    }
    __syncthreads();
  }
#pragma unroll
  for (int i = 0; i < 4; ++i) {
    float4 r;
    r.x = acc[i][0];
    r.y = acc[i][1];
    r.z = acc[i][2];
    r.w = acc[i][3];
    *(float4*)&out[(size_t)(m0 + (ty << 2) + i) * 1024 + n0 + (tx << 2)] = r;
  }
}

extern "C" void kernel_launch(void* const* d_in, const int* in_sizes, int n_in,
                              void* d_out, int out_size, void* d_ws,
                              size_t ws_size, hipStream_t stream) {
  const float* x = (const float*)d_in[0];
  const float* w1 = (const float*)d_in[1];
  const float* w2 = (const float*)d_in[2];
  float* ws = (float*)d_ws;
  float2* tab = (float2*)(ws + TAB_OFF);
  float* qws = ws + Q_OFF;
  float* kws = ws + K_OFF;
  float* vws = ws + V_OFF;
  float* ows = ws + O_OFF;
  float* out = (float*)d_out;

  hipLaunchKernelGGL(rope_table_kernel, dim3(256), dim3(256), 0, stream, tab);
  hipLaunchKernelGGL(gemm_qkv_rope, dim3(64 * 48), dim3(256), 0, stream, x, w1,
                     tab, qws, kws, vws);
  hipLaunchKernelGGL(attn_kernel, dim3(2 * 16 * 32), dim3(256), 0, stream, qws,
                     kws, vws, ows);
  hipLaunchKernelGGL(gemm_out, dim3(64 * 16), dim3(256), 0, stream, ows, w2,
                     out);
}

// Round 2
// 197.949 us; speedup vs baseline: 4.9441x; 4.9441x over previous
//
#include <hip/hip_runtime.h>
#include <math.h>

typedef unsigned short u16;
typedef unsigned int u32;
typedef float f32x4 __attribute__((ext_vector_type(4)));
typedef u32 u32x4 __attribute__((ext_vector_type(4)));

// ---- problem dims: B=2 S=2048 E=1024 H=16 HD=64 ----
// ---- ws byte offsets (total 46.7 MB; round-0 proved >=67 MB available) ----
static const size_t TAB_B  = 0;         // float2[2048][32]
static const size_t QBF_B  = 524288;    // bf16 [2][16][2048][64], pre-scaled 1/8
static const size_t KBF_B  = 8912896;   // bf16 [2][16][2048][64]
static const size_t VTB_B  = 17301504;  // bf16 [2][16][64][2048]  (V transposed)
static const size_t W2HI_B = 25690112;  // bf16 [1024][1024]
static const size_t W2LO_B = 27787264;
static const size_t XBF_B  = 29884416;  // bf16 x      (dead after QKV gemm)
static const size_t W1BF_B = 38273024;  // bf16 w1     (dead after QKV gemm)
static const size_t OHI_B  = 29884416;  // bf16 [4096][1024], reuses XBF
static const size_t OLO_B  = 38273024;  // bf16 [4096][1024], reuses W1BF

__device__ __forceinline__ u16 f2bf(float f) {
  u32 u = __builtin_bit_cast(u32, f);
  u += 0x7fffu + ((u >> 16) & 1u);
  return (u16)(u >> 16);
}
__device__ __forceinline__ float bf2f(u16 h) {
  return __builtin_bit_cast(float, (u32)h << 16);
}
// inline-asm MFMA: D/C = acc ("+v"), A, B as 4-VGPR tuples of packed bf16.
__device__ __forceinline__ void mfma16(f32x4& d, u32x4 a, u32x4 b) {
  asm volatile("v_mfma_f32_16x16x32_bf16 %0, %1, %2, %0"
               : "+v"(d)
               : "v"(a), "v"(b));
}
// async global->LDS, 16B per lane; lds dest must be wave-uniform base (+lane*16 by HW)
__device__ __forceinline__ void gld16(const void* g, void* l) {
  __builtin_amdgcn_global_load_lds(
      (const __attribute__((address_space(1))) void*)(void*)g,
      (__attribute__((address_space(3))) void*)l, 16, 0, 0);
}
// MFMA->VALU read hazard fence (inline-asm MFMAs: compiler can't insert these)
#define HZ() asm volatile("s_nop 7\ns_nop 7\ns_nop 7\ns_nop 7")

__global__ __launch_bounds__(256) void rope_table_kernel(float2* __restrict__ tab) {
  int idx = blockIdx.x * 256 + threadIdx.x;
  if (idx >= 2048 * 32) return;
  int s = idx >> 5;
  int i = idx & 31;
  double theta = pow(10000.0, -((double)(2 * i)) / 64.0);
  float ang = (float)s * (float)theta;
  tab[idx] = make_float2(cosf(ang), sinf(ang));
}

__global__ __launch_bounds__(256) void cvt_bf16_k(const float* __restrict__ in,
                                                  u16* __restrict__ out, int n4) {
  int i = blockIdx.x * 256 + threadIdx.x;
  const int stride = gridDim.x * 256;
  for (; i < n4; i += stride) {
    float4 v = ((const float4*)in)[i];
    ushort4 o;
    o.x = f2bf(v.x); o.y = f2bf(v.y); o.z = f2bf(v.z); o.w = f2bf(v.w);
    ((ushort4*)out)[i] = o;
  }
}

__global__ __launch_bounds__(256) void cvt_split_k(const float* __restrict__ in,
                                                   u16* __restrict__ hi,
                                                   u16* __restrict__ lo, int n4) {
  int i = blockIdx.x * 256 + threadIdx.x;
  const int stride = gridDim.x * 256;
  for (; i < n4; i += stride) {
    float4 v = ((const float4*)in)[i];
    ushort4 h, l;
    h.x = f2bf(v.x); h.y = f2bf(v.y); h.z = f2bf(v.z); h.w = f2bf(v.w);
    l.x = f2bf(v.x - bf2f(h.x));
    l.y = f2bf(v.y - bf2f(h.y));
    l.z = f2bf(v.z - bf2f(h.z));
    l.w = f2bf(v.w - bf2f(h.w));
    ((ushort4*)hi)[i] = h;
    ((ushort4*)lo)[i] = l;
  }
}

// ============================================================================
// B^T GEMM: C[m][n] = sum_k A[m][k]*B[n][k], lda=ldb=1024 (bf16), 128x128 tile,
// BK=64, 4 waves (2x2 of 64x64). global_load_lds staging with XOR-swizzled
// source (LDS stays linear); ds_read applies the same swizzle -> 2-way max.
// MODE 0: 1-pass (nkb=16), epilogue = RoPE + scatter q(scaled)/k/vT bf16.
// MODE 1: 3-pass hi/lo split (nkb=48), epilogue = f32 store to out.
// ============================================================================
template <int MODE>
__global__ __launch_bounds__(256) void gemm_bt(
    const u16* __restrict__ Ahi, const u16* __restrict__ Alo,
    const u16* __restrict__ Bhi, const u16* __restrict__ Blo, int nbn, int nkb,
    const float2* __restrict__ tab, u16* __restrict__ qd, u16* __restrict__ kd,
    u16* __restrict__ vtd, float* __restrict__ fout) {
  __shared__ __align__(16) char As[16384];  // [128 rows][64 k] bf16, swizzled
  __shared__ __align__(16) char Bs[16384];
  const int bm = blockIdx.x / nbn;
  const int bn = blockIdx.x % nbn;
  const int m0 = bm << 7;
  const int n0 = bn << 7;
  const int t = threadIdx.x;
  const int w = t >> 6;
  const int lane = t & 63;
  const int lr = lane & 15;  // A-row / B-col within 16
  const int lg = lane >> 4;  // k-group
  const int wr0 = (w >> 1) << 6;
  const int wc0 = (w & 1) << 6;
  const int srow0 = t >> 3;  // staging row (+32/round)
  const int sblk = t & 7;    // staging 16B-block within 128B row

  f32x4 acc[4][4];
#pragma unroll
  for (int mi = 0; mi < 4; ++mi)
#pragma unroll
    for (int ni = 0; ni < 4; ++ni) acc[mi][ni] = (f32x4)0.0f;

  for (int kb = 0; kb < nkb; ++kb) {
    const int pass = kb >> 4;
    const int k0 = (kb & 15) << 6;
    const u16* Ap = (MODE == 1 && pass == 2) ? Alo : Ahi;
    const u16* Bp = (MODE == 1 && pass == 1) ? Blo : Bhi;
    if (kb) __syncthreads();
#pragma unroll
    for (int r = 0; r < 4; ++r) {
      const int row = srow0 + (r << 5);
      const int g = sblk ^ (row & 7);  // inverse-swizzled source chunk
      gld16(Ap + (size_t)(m0 + row) * 1024 + k0 + (g << 3),
            As + (r << 12) + (w << 10));
      gld16(Bp + (size_t)(n0 + row) * 1024 + k0 + (g << 3),
            Bs + (r << 12) + (w << 10));
    }
    asm volatile("s_waitcnt vmcnt(0)" ::: "memory");
    __syncthreads();
#pragma unroll
    for (int kk = 0; kk < 2; ++kk) {
      u32x4 af[4], bf[4];
#pragma unroll
      for (int mi = 0; mi < 4; ++mi) {
        const int row = wr0 + (mi << 4) + lr;
        af[mi] = *(const u32x4*)(As + row * 128 +
                                 ((((kk << 2) + lg) ^ (row & 7)) << 4));
      }
#pragma unroll
      for (int ni = 0; ni < 4; ++ni) {
        const int row = wc0 + (ni << 4) + lr;
        bf[ni] = *(const u32x4*)(Bs + row * 128 +
                                 ((((kk << 2) + lg) ^ (row & 7)) << 4));
      }
      asm volatile("s_nop 1");
#pragma unroll
      for (int mi = 0; mi < 4; ++mi)
#pragma unroll
        for (int ni = 0; ni < 4; ++ni) mfma16(acc[mi][ni], af[mi], bf[ni]);
    }
  }
  HZ();
  // epilogue: D[row = 4*lg + i][col = lr] per fragment (measured C/D layout)
#pragma unroll
  for (int mi = 0; mi < 4; ++mi)
#pragma unroll
    for (int ni = 0; ni < 4; ++ni)
#pragma unroll
      for (int i = 0; i < 4; ++i) {
        float val = acc[mi][ni][i];
        const int grow = m0 + wr0 + (mi << 4) + (lg << 2) + i;
        const int col = n0 + wc0 + (ni << 4) + lr;
        if (MODE == 0) {
          const int b = grow >> 11, s = grow & 2047;
          const int which = col >> 10, hh = (col >> 6) & 15, d = col & 63;
          const size_t base = (size_t)((b << 4) + hh);
          if (which == 2) {
            vtd[(base * 64 + d) * 2048 + s] = f2bf(val);
          } else {
            float other = __shfl_xor(val, 1);  // neighbor col (pair element)
            float2 cs = tab[(s << 5) + (d >> 1)];
            float r = (d & 1) ? fmaf(val, cs.x, other * cs.y)
                              : fmaf(val, cs.x, -other * cs.y);
            if (which == 0) r *= 0.125f;  // fold 1/sqrt(HD) into q (exact)
            u16* dst = which ? kd : qd;
            dst[(base * 2048 + s) * 64 + d] = f2bf(r);
          }
        } else {
          fout[(size_t)grow * 1024 + col] = val;
        }
      }
}

// ============================================================================
// Flash attention, bf16 MFMA. 1 block = (b,h,64-row q tile); 4 waves x 16 rows.
// Swapped QK^T (S^T = K*Q^T) -> row softmax needs only shfl_xor 16/32.
// P -> padded per-wave LDS -> A-operand of normal PV against V^T tile.
// ============================================================================
__global__ __launch_bounds__(256) void attn_mfma(
    const u16* __restrict__ q, const u16* __restrict__ k,
    const u16* __restrict__ vt, u16* __restrict__ ohi, u16* __restrict__ olo) {
  __shared__ __align__(16) char Ks[8192];        // [64 j][64 d] swizzled
  __shared__ __align__(16) char Vs[8192];        // [64 dd][64 j] swizzled
  __shared__ __align__(16) u16 Ps[4][16][72];    // per-wave P[q][j], pad 72
  // XCD-aware remap: consecutive-on-XCD blocks share (b,h) -> K/V L2-resident
  const int bid = blockIdx.x;
  const int swz = (bid & 7) * 128 + (bid >> 3);
  const int qt = swz & 31;
  const int hh = (swz >> 5) & 15;
  const int b = swz >> 9;
  const int t = threadIdx.x;
  const int w = t >> 6;
  const int lane = t & 63;
  const int lr = lane & 15;
  const int lg = lane >> 4;

  const size_t bh = (size_t)((b << 4) + hh);
  const u16* qb = q + (bh * 2048 + (size_t)qt * 64 + w * 16) * 64;
  const u16* kb = k + bh * 2048 * 64;
  const u16* vb = vt + bh * 64 * 2048;

  // Q fragments (q rows = lr of this wave's 16; d slot = kk*32 + 8*lg + i)
  u32x4 qf[2];
  qf[0] = *(const u32x4*)(qb + lr * 64 + lg * 8);
  qf[1] = *(const u32x4*)(qb + lr * 64 + 32 + lg * 8);

  f32x4 oacc[4];
#pragma unroll
  for (int ddb = 0; ddb < 4; ++ddb) oacc[ddb] = (f32x4)0.0f;
  float mrow = -3.0e38f, lrow = 0.0f;  // stats for q = lr

  for (int kt = 0; kt < 32; ++kt) {
    if (kt) __syncthreads();
    const u16* ksrc = kb + kt * 4096;  // contiguous 64x64 tile
#pragma unroll
    for (int r = 0; r < 2; ++r) {
      const int row = (t >> 3) + (r << 5);
      const int g = (t & 7) ^ (row & 7);
      gld16(ksrc + row * 64 + (g << 3), Ks + (r << 12) + (w << 10));
      gld16(vb + (size_t)row * 2048 + kt * 64 + (g << 3),
            Vs + (r << 12) + (w << 10));
    }
    asm volatile("s_waitcnt vmcnt(0)" ::: "memory");
    __syncthreads();
    // S^T[j][q] = K * Q^T : A-frag = K rows j, B-frag = Q (col q = lr)
    f32x4 sacc[4];
#pragma unroll
    for (int jb = 0; jb < 4; ++jb) sacc[jb] = (f32x4)0.0f;
#pragma unroll
    for (int kk = 0; kk < 2; ++kk) {
      u32x4 kf[4];
#pragma unroll
      for (int jb = 0; jb < 4; ++jb) {
        const int row = (jb << 4) + lr;
        kf[jb] = *(const u32x4*)(Ks + row * 128 +
                                 ((((kk << 2) + lg) ^ (row & 7)) << 4));
      }
      asm volatile("s_nop 1");
#pragma unroll
      for (int jb = 0; jb < 4; ++jb) mfma16(sacc[jb], kf[jb], qf[kk]);
    }
    HZ();
    // online softmax over j for this lane's q = lr (S^T row j = jb*16+4*lg+i)
    float pmax = -3.0e38f;
#pragma unroll
    for (int jb = 0; jb < 4; ++jb)
#pragma unroll
      for (int i = 0; i < 4; ++i) pmax = fmaxf(pmax, sacc[jb][i]);
    pmax = fmaxf(pmax, __shfl_xor(pmax, 16));
    pmax = fmaxf(pmax, __shfl_xor(pmax, 32));
    const float mnew = fmaxf(mrow, pmax);
    const float fac = __expf(mrow - mnew);
    mrow = mnew;
    float lsum = 0.0f;
#pragma unroll
    for (int jb = 0; jb < 4; ++jb)
#pragma unroll
      for (int i = 0; i < 4; ++i) {
        const float p = __expf(sacc[jb][i] - mnew);
        sacc[jb][i] = p;
        lsum += p;
      }
    lsum += __shfl_xor(lsum, 16);
    lsum += __shfl_xor(lsum, 32);
    lrow = lrow * fac + lsum;
    // P -> LDS (bf16, pair-packed b32 writes; 2-way max conflicts via pad 72)
#pragma unroll
    for (int jb = 0; jb < 4; ++jb) {
      const u32 p01 = (u32)f2bf(sacc[jb][0]) | ((u32)f2bf(sacc[jb][1]) << 16);
      const u32 p23 = (u32)f2bf(sacc[jb][2]) | ((u32)f2bf(sacc[jb][3]) << 16);
      *(u32*)(&Ps[w][lr][(jb << 4) + (lg << 2)]) = p01;
      *(u32*)(&Ps[w][lr][(jb << 4) + (lg << 2) + 2]) = p23;
    }
    // rescale O (rows q = 4*lg + i) by fac broadcast from lane (4*lg+i)
    float fci[4];
#pragma unroll
    for (int i = 0; i < 4; ++i) fci[i] = __shfl(fac, (lg << 2) + i);
#pragma unroll
    for (int ddb = 0; ddb < 4; ++ddb)
#pragma unroll
      for (int i = 0; i < 4; ++i) oacc[ddb][i] *= fci[i];
    // PV: A = P[q=lr][j-slot], B = V^T rows dd; k-dim = j (slot maps match)
    asm volatile("s_nop 3");
#pragma unroll
    for (int kk = 0; kk < 2; ++kk) {
      const u32x4 pf = *(const u32x4*)(&Ps[w][lr][(kk << 5) + (lg << 3)]);
#pragma unroll
      for (int ddb = 0; ddb < 4; ++ddb) {
        const int row = (ddb << 4) + lr;
        const u32x4 vf = *(const u32x4*)(Vs + row * 128 +
                                         ((((kk << 2) + lg) ^ (row & 7)) << 4));
        mfma16(oacc[ddb], pf, vf);
      }
    }
  }
  HZ();
  // epilogue: normalize rows, split hi/lo bf16, write o[b][s][h*64+dd]
  const float invl = 1.0f / lrow;  // for q = lr
  float inv[4];
#pragma unroll
  for (int i = 0; i < 4; ++i) inv[i] = __shfl(invl, (lg << 2) + i);
#pragma unroll
  for (int ddb = 0; ddb < 4; ++ddb)
#pragma unroll
    for (int i = 0; i < 4; ++i) {
      const float vO = oacc[ddb][i] * inv[i];
      const u16 h = f2bf(vO);
      const u16 l = f2bf(vO - bf2f(h));
      const size_t srow = (size_t)(b * 2048 + (qt << 6) + (w << 4) + (lg << 2) + i);
      const int col = (hh << 6) + (ddb << 4) + lr;
      ohi[srow * 1024 + col] = h;
      olo[srow * 1024 + col] = l;
    }
}

extern "C" void kernel_launch(void* const* d_in, const int* in_sizes, int n_in,
                              void* d_out, int out_size, void* d_ws,
                              size_t ws_size, hipStream_t stream) {
  const float* x = (const float*)d_in[0];
  const float* w1 = (const float*)d_in[1];
  const float* w2 = (const float*)d_in[2];
  char* ws = (char*)d_ws;
  float2* tab = (float2*)(ws + TAB_B);
  u16* qbf = (u16*)(ws + QBF_B);
  u16* kbf = (u16*)(ws + KBF_B);
  u16* vtbf = (u16*)(ws + VTB_B);
  u16* w2hi = (u16*)(ws + W2HI_B);
  u16* w2lo = (u16*)(ws + W2LO_B);
  u16* xbf = (u16*)(ws + XBF_B);
  u16* w1bf = (u16*)(ws + W1BF_B);
  u16* ohi = (u16*)(ws + OHI_B);
  u16* olo = (u16*)(ws + OLO_B);
  float* out = (float*)d_out;

  rope_table_kernel<<<dim3(256), dim3(256), 0, stream>>>(tab);
  cvt_bf16_k<<<dim3(1024), dim3(256), 0, stream>>>(x, xbf, 4194304 / 4);
  cvt_bf16_k<<<dim3(768), dim3(256), 0, stream>>>(w1, w1bf, 3145728 / 4);
  cvt_split_k<<<dim3(256), dim3(256), 0, stream>>>(w2, w2hi, w2lo, 1048576 / 4);
  gemm_bt<0><<<dim3(32 * 24), dim3(256), 0, stream>>>(
      xbf, xbf, w1bf, w1bf, 24, 16, tab, qbf, kbf, vtbf, nullptr);
  attn_mfma<<<dim3(1024), dim3(256), 0, stream>>>(qbf, kbf, vtbf, ohi, olo);
  gemm_bt<1><<<dim3(32 * 8), dim3(256), 0, stream>>>(
      ohi, olo, w2hi, w2lo, 8, 48, nullptr, nullptr, nullptr, nullptr, out);
}